// Round 4
// baseline (690.962 us; speedup 1.0000x reference)
//
#include <hip/hip_runtime.h>
#include <hip/hip_fp16.h>

#define B 32
#define NW2V 300
#define NR 200

// r_T[j][b] = bias[j] + sum_k q[b][k] * W[k][j]   -> [N_R, B] layout, fp32
__global__ void compute_r_kernel(const float* __restrict__ q,
                                 const float* __restrict__ W,
                                 const float* __restrict__ bias,
                                 float* __restrict__ rT) {
    int tid = blockIdx.x * blockDim.x + threadIdx.x;
    if (tid >= NR * B) return;
    int b = tid & (B - 1);
    int j = tid >> 5;
    float acc = bias[j];
    for (int k = 0; k < NW2V; ++k)
        acc += q[b * NW2V + k] * W[k * NR + j];
    rT[j * B + b] = acc;
}

// x [B, N_E] f32 -> xT [N_E, B] f16, LDS-tiled, coalesced both sides
__global__ void transpose_in_kernel(const float* __restrict__ x,
                                    __half* __restrict__ xT, int n_e) {
    __shared__ float tile[64][33];
    int e0 = blockIdx.x * 64;
    for (int p = 0; p < 8; ++p) {
        int idx = p * 256 + threadIdx.x;
        int b = idx >> 6, e = idx & 63;
        if (e0 + e < n_e) tile[e][b] = x[(size_t)b * n_e + e0 + e];
    }
    __syncthreads();
    for (int p = 0; p < 8; ++p) {
        int idx = p * 256 + threadIdx.x;
        int b = idx & 31, e = idx >> 5;
        if (e0 + e < n_e) xT[(size_t)(e0 + e) * B + b] = __float2half(tile[e][b]);
    }
}

// xT [N_E, B] f16 -> out [B, N_E] f32
__global__ void transpose_out_kernel(const __half* __restrict__ xT,
                                     float* __restrict__ out, int n_e) {
    __shared__ float tile[64][33];
    int e0 = blockIdx.x * 64;
    for (int p = 0; p < 8; ++p) {
        int idx = p * 256 + threadIdx.x;
        int b = idx & 31, e = idx >> 5;
        if (e0 + e < n_e) tile[e][b] = __half2float(xT[(size_t)(e0 + e) * B + b]);
    }
    __syncthreads();
    for (int p = 0; p < 8; ++p) {
        int idx = p * 256 + threadIdx.x;
        int b = idx >> 6, e = idx & 63;
        if (e0 + e < n_e) out[(size_t)b * n_e + e0 + e] = tile[e][b];
    }
}

// ---- counting sort of triples by obj (indices identical across all 3 hops) ----

__global__ void hist_kernel(const int* __restrict__ obj,
                            int* __restrict__ counts, int n_t) {
    int t = blockIdx.x * 256 + threadIdx.x;
    if (t < n_t) atomicAdd(&counts[obj[t]], 1);
}

// Phase A: per-256-bin block sums
__global__ void block_reduce_kernel(const int* __restrict__ counts,
                                    int* __restrict__ blockSums, int n_e) {
    __shared__ int s[256];
    int i = blockIdx.x * 256 + threadIdx.x;
    s[threadIdx.x] = (i < n_e) ? counts[i] : 0;
    __syncthreads();
    for (int off = 128; off > 0; off >>= 1) {
        if (threadIdx.x < off) s[threadIdx.x] += s[threadIdx.x + off];
        __syncthreads();
    }
    if (threadIdx.x == 0) blockSums[blockIdx.x] = s[0];
}

// Phase B: single-block exclusive scan of blockSums[nb], nb <= 2048
__global__ void scan_blocksums_kernel(int* __restrict__ blockSums, int nb) {
    __shared__ int s[256];
    int t = threadIdx.x;
    int local[8];
    int run = 0;
    for (int c = 0; c < 8; ++c) {
        int j = t * 8 + c;
        run += (j < nb) ? blockSums[j] : 0;
        local[c] = run;                         // inclusive within thread
    }
    s[t] = run;
    __syncthreads();
    for (int off = 1; off < 256; off <<= 1) {
        int v = (t >= off) ? s[t - off] : 0;
        __syncthreads();
        s[t] += v;
        __syncthreads();
    }
    int threadExcl = s[t] - run;
    for (int c = 0; c < 8; ++c) {
        int j = t * 8 + c;
        if (j < nb) blockSums[j] = threadExcl + (c == 0 ? 0 : local[c - 1]);
    }
}

// Phase C: offsets[i] = exclusive scan of counts; cursor = copy; offsets[n_e]=n_t
__global__ void scan_counts_kernel(const int* __restrict__ counts,
                                   const int* __restrict__ blockSums,
                                   int* __restrict__ offsets,
                                   int* __restrict__ cursor, int n_e, int n_t) {
    __shared__ int s[256];
    int t = threadIdx.x;
    int i = blockIdx.x * 256 + t;
    int c = (i < n_e) ? counts[i] : 0;
    s[t] = c;
    __syncthreads();
    for (int off = 1; off < 256; off <<= 1) {
        int v = (t >= off) ? s[t - off] : 0;
        __syncthreads();
        s[t] += v;
        __syncthreads();
    }
    if (i < n_e) {
        int o = blockSums[blockIdx.x] + s[t] - c;   // exclusive
        offsets[i] = o;
        cursor[i] = o;
    }
    if (i == 0) offsets[n_e] = n_t;
}

// pack subj (19 bits, N_E<2^19) | rel<<19 (8 bits, N_R<256) and bucket by obj
__global__ void scatter_kernel(const int* __restrict__ subj,
                               const int* __restrict__ rel,
                               const int* __restrict__ obj,
                               int* __restrict__ cursor,
                               unsigned int* __restrict__ packed, int n_t) {
    int t = blockIdx.x * 256 + threadIdx.x;
    if (t >= n_t) return;
    int o = obj[t];
    int pos = atomicAdd(&cursor[o], 1);
    packed[pos] = (unsigned)subj[t] | ((unsigned)rel[t] << 19);
}

// One follow step, atomic-free: 16 lanes per ENTITY, fp32 accumulate over the
// entity's sorted triple segment, single half2 store per lane.
__global__ void hop_sorted_kernel(const __half* __restrict__ xT,
                                  const float* __restrict__ rT,
                                  __half* __restrict__ outT,
                                  const unsigned int* __restrict__ packed,
                                  const int* __restrict__ offsets,
                                  const int* __restrict__ n_hop,
                                  int hop, int n_e) {
    int tid = blockIdx.x * 256 + threadIdx.x;
    if (*n_hop < hop) {                 // degenerate: identity pass-through
        if (tid < n_e * 16) ((__half2*)outT)[tid] = ((const __half2*)xT)[tid];
        return;
    }
    int g = tid >> 4;
    if (g >= n_e) return;
    int l = tid & 15;                   // batch-pair index
    int beg = offsets[g], end = offsets[g + 1];
    float a0 = 0.f, a1 = 0.f;
    for (int i = beg; i < end; ++i) {
        unsigned p = packed[i];         // broadcast across the 16-lane group
        int s = p & 0x7FFFF;
        int r = p >> 19;
        __half2 xh = ((const __half2*)xT)[s * 16 + l];   // random 64B/group gather
        float2  rf = ((const float2*)rT)[r * 16 + l];    // L1-resident
        a0 += __half2float(xh.x) * rf.x;
        a1 += __half2float(xh.y) * rf.y;
    }
    ((__half2*)outT)[g * 16 + l] = __floats2half2_rn(a0, a1);
}

extern "C" void kernel_launch(void* const* d_in, const int* in_sizes, int n_in,
                              void* d_out, int out_size, void* d_ws, size_t ws_size,
                              hipStream_t stream) {
    const float* x    = (const float*)d_in[0];
    const float* q    = (const float*)d_in[1];
    const int*   subj = (const int*)d_in[2];
    const int*   rel  = (const int*)d_in[3];
    const int*   obj  = (const int*)d_in[4];
    const float* W1   = (const float*)d_in[5];
    const float* bb1  = (const float*)d_in[6];
    const float* W2   = (const float*)d_in[7];
    const float* bb2  = (const float*)d_in[8];
    const float* W3   = (const float*)d_in[9];
    const float* bb3  = (const float*)d_in[10];
    const int*   n_hop = (const int*)d_in[11];
    float* out = (float*)d_out;

    const int n_e = in_sizes[0] / B;    // 500000
    const int n_t = in_sizes[2];        // 2000000
    const int nb  = (n_e + 255) / 256;  // scan blocks (1954, must be <= 2048)

    // ws layout (~78 MB of 128 MB):
    __half* bufA   = (__half*)d_ws;                       // [N_E, B] f16, 32 MB
    __half* bufB   = bufA + (size_t)n_e * B;              // [N_E, B] f16, 32 MB
    float*  rT     = (float*)(bufB + (size_t)n_e * B);    // 3*[N_R,B] f32, 75 KB
    int*    counts = (int*)(rT + 3 * NR * B);             // [N_E]
    int*    offs   = counts + n_e;                        // [N_E+1]
    int*    cursor = offs + n_e + 1;                      // [N_E]
    int*    bsums  = cursor + n_e;                        // [nb]
    unsigned int* packed = (unsigned int*)(bsums + nb);   // [N_T], 8 MB

    const int rblocks = (NR * B + 255) / 256;
    compute_r_kernel<<<rblocks, 256, 0, stream>>>(q, W1, bb1, rT + 0 * NR * B);
    compute_r_kernel<<<rblocks, 256, 0, stream>>>(q, W2, bb2, rT + 1 * NR * B);
    compute_r_kernel<<<rblocks, 256, 0, stream>>>(q, W3, bb3, rT + 2 * NR * B);

    const int tblocks = (n_e + 63) / 64;
    transpose_in_kernel<<<tblocks, 256, 0, stream>>>(x, bufA, n_e);

    // --- counting sort by obj (once; shared by all 3 hops) ---
    hipMemsetAsync(counts, 0, (size_t)n_e * sizeof(int), stream);
    const int t256 = (n_t + 255) / 256;
    hist_kernel<<<t256, 256, 0, stream>>>(obj, counts, n_t);
    block_reduce_kernel<<<nb, 256, 0, stream>>>(counts, bsums, n_e);
    scan_blocksums_kernel<<<1, 256, 0, stream>>>(bsums, nb);
    scan_counts_kernel<<<nb, 256, 0, stream>>>(counts, bsums, offs, cursor, n_e, n_t);
    scatter_kernel<<<t256, 256, 0, stream>>>(subj, rel, obj, cursor, packed, n_t);

    // --- 3 atomic-free hops ---
    const int hblocks = (n_e * 16 + 255) / 256;
    hop_sorted_kernel<<<hblocks, 256, 0, stream>>>(bufA, rT + 0 * NR * B, bufB,
                                                   packed, offs, n_hop, 1, n_e);
    hop_sorted_kernel<<<hblocks, 256, 0, stream>>>(bufB, rT + 1 * NR * B, bufA,
                                                   packed, offs, n_hop, 2, n_e);
    hop_sorted_kernel<<<hblocks, 256, 0, stream>>>(bufA, rT + 2 * NR * B, bufB,
                                                   packed, offs, n_hop, 3, n_e);

    transpose_out_kernel<<<tblocks, 256, 0, stream>>>(bufB, out, n_e);
}